// Round 1
// baseline (78319.141 us; speedup 1.0000x reference)
//
#include <hip/hip_runtime.h>
#include <float.h>

// Batched transducer greedy decode, B=32 T=1000 H=640 V=5000, fp32.
// Pipeline: [precompute xWxb] -> init -> 1000 x (w1: GEMMs+partials ; w2: reduce+gates+update)
#define BB 32
#define TT 1000
#define HH 640
#define H4 2560
#define VV 5000
#define NLOG 157   // logits blocks, 32 cols each (last block 8 valid cols)
#define NWH  80    // h@Wh blocks, 32 cols each (2560 exact)
#define NBLK 237

// workspace layout (float offsets)
#define O_JOINT 0        // jointT[j][b]  (640x32) = tanh(tn_t + out_PN), transposed
#define O_HT    20480    // hT[j][b]      (640x32)
#define O_HWH   40960    // hwh[b][col]   (32x2560)
#define O_CT    122880   // cT[j][b]
#define O_PNT   143360   // pnT[j][b]  (out_PN)
#define O_PM    163840   // partial max   [157*32]
#define O_PS    168864   // partial sumexp[157*32]
#define O_PI    173888   // partial argmax[157*32] (int bits in float)
#define O_TOK   178912   // tok[32] (int bits)
#define O_SC    178944   // scores[32]
#define O_XWXB  180224   // embed@Wx + b  (5000x2560), optional
#define XWXB_ELEMS ((size_t)VV * (size_t)H4)

__device__ __forceinline__ float sigf(float x) { return 1.0f / (1.0f + expf(-x)); }

// ---------------- precompute: xwxb[v][col] = sum_k embed[v][k]*Wx[k][col] + b[col]
__global__ __launch_bounds__(256) void precompute_k(const float* __restrict__ embed,
                                                    const float* __restrict__ Wx,
                                                    const float* __restrict__ bias,
                                                    float* __restrict__ xwxb) {
  __shared__ float emb[16 * HH];  // 40 KB
  const int tid = threadIdx.x;
  const int v0 = blockIdx.y * 16;
  const int col = blockIdx.x * 256 + tid;
  for (int i = tid; i < 16 * HH; i += 256) {
    int r = i / HH;
    int k = i - r * HH;
    int v = v0 + r; if (v >= VV) v = VV - 1;
    emb[i] = embed[(size_t)v * HH + k];
  }
  __syncthreads();
  float acc[16];
#pragma unroll
  for (int v = 0; v < 16; ++v) acc[v] = 0.0f;
  for (int k = 0; k < HH; ++k) {
    float w = Wx[(size_t)k * H4 + col];
#pragma unroll
    for (int v = 0; v < 16; ++v) acc[v] += emb[v * HH + k] * w;
  }
  float bv = bias[col];
#pragma unroll
  for (int v = 0; v < 16; ++v)
    if (v0 + v < VV) xwxb[(size_t)(v0 + v) * H4 + col] = acc[v] + bv;
}

// ---------------- init: tok=0, scores=0, initial LSTM step (h0=c0=0, tok=0), jointT for t=0
__global__ __launch_bounds__(256) void init_k(const float* __restrict__ tn,
                                              const float* __restrict__ embed,
                                              const float* __restrict__ Wx,
                                              const float* __restrict__ bias,
                                              float* __restrict__ ws, int use_table) {
  __shared__ float xl[HH];  // embed row 0 (path B)
  const int tid = threadIdx.x, bid = blockIdx.x;
  if (bid == 0 && tid < BB) { ws[O_TOK + tid] = __int_as_float(0); ws[O_SC + tid] = 0.0f; }
  const int j0 = (bid * HH) / NBLK, j1 = ((bid + 1) * HH) / NBLK;
  const int nj = j1 - j0;
  const int p = tid;
  const bool act = p < nj * BB;
  int b = 0, j = 0;
  float g4[4] = {0, 0, 0, 0};
  if (act) {
    b = p & 31; j = j0 + (p >> 5);
    const float* xwxb = ws + O_XWXB;
#pragma unroll
    for (int g = 0; g < 4; ++g) {
      int col = g * HH + j;
      g4[g] = use_table ? xwxb[col] : bias[col];
    }
  }
  if (!use_table) {
    for (int i = tid; i < HH; i += 256) xl[i] = embed[i];  // row 0
    __syncthreads();
    if (act) {
      for (int k = 0; k < HH; ++k) {
        float xv = xl[k];
#pragma unroll
        for (int g = 0; g < 4; ++g) g4[g] += xv * Wx[(size_t)k * H4 + (g * HH + j)];
      }
    }
  }
  if (act) {
    float c1 = sigf(g4[1]) * 0.0f + sigf(g4[0]) * tanhf(g4[2]);
    float h1 = sigf(g4[3]) * tanhf(c1);
    ws[O_CT + j * BB + b] = c1;
    ws[O_HT + j * BB + b] = h1;
    ws[O_PNT + j * BB + b] = h1;
    ws[O_JOINT + j * BB + b] = tanhf(tn[((size_t)b * TT + 0) * HH + j] + h1);
  }
}

// ---------------- w1: logits GEMM (+online softmax partials) and h@Wh GEMM
__global__ __launch_bounds__(256) void w1_k(const float* __restrict__ Wc,
                                            const float* __restrict__ Wh,
                                            const float* __restrict__ bc,
                                            float* __restrict__ ws) {
  const int tid = threadIdx.x, bid = blockIdx.x;
  const int lane = tid & 31, bq = tid >> 5;  // bq in [0,8): rows bq*4..bq*4+3
  if (bid < NLOG) {
    const int c = bid * 32 + lane;
    const int cc = (c < VV) ? c : (VV - 1);
    const float* act = ws + O_JOINT + bq * 4;
    const float* wp = Wc + cc;
    float a0 = 0, a1 = 0, a2 = 0, a3 = 0;
#pragma unroll 4
    for (int k = 0; k < HH; ++k) {
      float4 av = *(const float4*)(act + k * 32);
      float w = wp[(size_t)k * VV];
      a0 += av.x * w; a1 += av.y * w; a2 += av.z * w; a3 += av.w * w;
    }
    float bcv = bc[cc];
    float l[4];
    bool valid = (c < VV);
    l[0] = valid ? a0 + bcv : -FLT_MAX;
    l[1] = valid ? a1 + bcv : -FLT_MAX;
    l[2] = valid ? a2 + bcv : -FLT_MAX;
    l[3] = valid ? a3 + bcv : -FLT_MAX;
#pragma unroll
    for (int i = 0; i < 4; ++i) {
      float m = l[i]; int ix = c;
      // first-index tie-break argmax + max, within the 32-lane half-wave
      for (int d = 1; d < 32; d <<= 1) {
        float om = __shfl_xor(m, d);
        int oi = __shfl_xor(ix, d);
        if (om > m || (om == m && oi < ix)) { m = om; ix = oi; }
      }
      float e = expf(l[i] - m);  // masked lanes: -inf -> 0
      for (int d = 1; d < 32; d <<= 1) e += __shfl_xor(e, d);
      if (lane == 0) {
        int r = bq * 4 + i;
        ws[O_PM + bid * 32 + r] = m;
        ws[O_PS + bid * 32 + r] = e;
        ws[O_PI + bid * 32 + r] = __int_as_float(ix);
      }
    }
  } else if (bid < NLOG + NWH) {
    const int c = (bid - NLOG) * 32 + lane;
    const float* act = ws + O_HT + bq * 4;
    const float* wp = Wh + c;
    float a0 = 0, a1 = 0, a2 = 0, a3 = 0;
#pragma unroll 4
    for (int k = 0; k < HH; ++k) {
      float4 av = *(const float4*)(act + k * 32);
      float w = wp[(size_t)k * H4];
      a0 += av.x * w; a1 += av.y * w; a2 += av.z * w; a3 += av.w * w;
    }
    ws[O_HWH + (size_t)(bq * 4 + 0) * H4 + c] = a0;
    ws[O_HWH + (size_t)(bq * 4 + 1) * H4 + c] = a1;
    ws[O_HWH + (size_t)(bq * 4 + 2) * H4 + c] = a2;
    ws[O_HWH + (size_t)(bq * 4 + 3) * H4 + c] = a3;
  }
}

// ---------------- w2: redundant reduce -> argmax/val/upd ; gates ; state update ; next joint
__global__ __launch_bounds__(256) void w2_k(const float* __restrict__ tn,
                                            const float* __restrict__ embed,
                                            const float* __restrict__ Wx,
                                            const float* __restrict__ bias,
                                            float* __restrict__ out,
                                            float* __restrict__ ws,
                                            int use_table, int t) {
  __shared__ float rm[8][BB];
  __shared__ float rs[8][BB];
  __shared__ int ri[8][BB];
  __shared__ int s_tok[BB];
  __shared__ int s_upd[BB];
  __shared__ float xl[BB * 321];  // path B: 32 rows x 320 k (half), padded stride
  const int tid = threadIdx.x, bid = blockIdx.x;
  const int r = tid & 31, c8 = tid >> 5;

  // (a) redundant argmax / logsumexp reduce over the 157 block partials
  {
    int g0 = (c8 * NLOG) >> 3, g1 = ((c8 + 1) * NLOG) >> 3;
    float m = -FLT_MAX, s = 0.0f; int ix = 0;
    for (int g = g0; g < g1; ++g) {
      float M = ws[O_PM + g * 32 + r];
      float S = ws[O_PS + g * 32 + r];
      int I = __float_as_int(ws[O_PI + g * 32 + r]);
      if (M > m) { s = s * expf(m - M) + S; m = M; ix = I; }
      else       { s += S * expf(M - m); }
    }
    rm[c8][r] = m; rs[c8][r] = s; ri[c8][r] = ix;
  }
  __syncthreads();
  if (tid < BB) {
    float m = rm[0][tid], s = rs[0][tid]; int ix = ri[0][tid];
#pragma unroll
    for (int q = 1; q < 8; ++q) {
      float M = rm[q][tid], S = rs[q][tid]; int I = ri[q][tid];
      if (M > m) { s = s * expf(m - M) + S; m = M; ix = I; }
      else       { s += S * expf(M - m); }
    }
    int pos = ix;
    int upd = (pos != 0) ? 1 : 0;
    int tk = __float_as_int(ws[O_TOK + tid]);
    int ntk = upd ? pos : tk;
    s_tok[tid] = ntk;
    s_upd[tid] = upd;
    if (bid == 0) {
      ws[O_TOK + tid] = __int_as_float(ntk);
      float sc = ws[O_SC + tid];
      if (upd) sc += -logf(s);  // val = max - logsumexp = -log(S)
      ws[O_SC + tid] = sc;
      out[BB + (size_t)tid * TT + t] = upd ? (float)pos : 0.0f;
      if (t == TT - 1) out[tid] = sc;
    }
  }
  __syncthreads();

  // (b) gates + masked state update + next joint, for this block's j-slice
  const int j0 = (bid * HH) / NBLK, j1 = ((bid + 1) * HH) / NBLK;
  const int nj = j1 - j0;
  const int p = tid;
  const bool act = p < nj * BB;
  int b = 0, j = 0;
  float g4[4] = {0, 0, 0, 0};
  if (act) {
    b = p & 31; j = j0 + (p >> 5);
    int tk = s_tok[b];
    const float* xwxb = ws + O_XWXB;
#pragma unroll
    for (int g = 0; g < 4; ++g) {
      int col = g * HH + j;
      float base = ws[O_HWH + (size_t)b * H4 + col];
      g4[g] = base + (use_table ? xwxb[(size_t)tk * H4 + col] : bias[col]);
    }
  }
  if (!use_table) {
    // x@Wx inline, staged in 2 k-halves (LDS budget)
    for (int half = 0; half < 2; ++half) {
      int k0 = half * 320;
      __syncthreads();
      for (int i = tid; i < BB * 320; i += 256) {
        int bb = i / 320;
        int kk = i - bb * 320;
        xl[bb * 321 + kk] = embed[(size_t)s_tok[bb] * HH + k0 + kk];
      }
      __syncthreads();
      if (act) {
        for (int k = 0; k < 320; ++k) {
          float xv = xl[b * 321 + k];
#pragma unroll
          for (int g = 0; g < 4; ++g) g4[g] += xv * Wx[(size_t)(k0 + k) * H4 + (g * HH + j)];
        }
      }
    }
  }
  if (act) {
    float ci = ws[O_CT + j * BB + b];
    float c2 = sigf(g4[1]) * ci + sigf(g4[0]) * tanhf(g4[2]);
    float h2 = sigf(g4[3]) * tanhf(c2);
    float pv;
    if (s_upd[b]) {
      ws[O_CT + j * BB + b] = c2;
      ws[O_HT + j * BB + b] = h2;
      ws[O_PNT + j * BB + b] = h2;
      pv = h2;
    } else {
      pv = ws[O_PNT + j * BB + b];
    }
    if (t + 1 < TT)
      ws[O_JOINT + j * BB + b] = tanhf(tn[((size_t)b * TT + (t + 1)) * HH + j] + pv);
  }
}

extern "C" void kernel_launch(void* const* d_in, const int* in_sizes, int n_in,
                              void* d_out, int out_size, void* d_ws, size_t ws_size,
                              hipStream_t stream) {
  const float* tn    = (const float*)d_in[0];
  const float* embed = (const float*)d_in[1];
  const float* Wx    = (const float*)d_in[2];
  const float* Wh    = (const float*)d_in[3];
  const float* bias  = (const float*)d_in[4];
  const float* Wc    = (const float*)d_in[5];
  const float* bc    = (const float*)d_in[6];
  float* out = (float*)d_out;
  float* ws  = (float*)d_ws;

  const size_t need_table = (size_t)(O_XWXB + XWXB_ELEMS) * sizeof(float);
  const int use_table = (ws_size >= need_table) ? 1 : 0;

  if (use_table)
    hipLaunchKernelGGL(precompute_k, dim3(H4 / 256, (VV + 15) / 16), dim3(256), 0, stream,
                       embed, Wx, bias, ws + O_XWXB);
  hipLaunchKernelGGL(init_k, dim3(NBLK), dim3(256), 0, stream, tn, embed, Wx, bias, ws, use_table);
  for (int t = 0; t < TT; ++t) {
    hipLaunchKernelGGL(w1_k, dim3(NBLK), dim3(256), 0, stream, Wc, Wh, bc, ws);
    hipLaunchKernelGGL(w2_k, dim3(NBLK), dim3(256), 0, stream, tn, embed, Wx, bias, out, ws,
                       use_table, t);
  }
}

// Round 2
// 47301.819 us; speedup vs baseline: 1.6557x; 1.6557x over previous
//
#include <hip/hip_runtime.h>
#include <float.h>

// Batched transducer greedy decode, B=32 T=1000 H=640 V=5000, fp32.
// [precompute xWxb] -> init -> 1000 x (w1: K-split GEMMs+softmax partials ; w2: reduce+gates+update)
#define BB 32
#define TT 1000
#define HH 640
#define H4 2560
#define VV 5000
#define NLOG 157   // logits blocks, 32 cols each (last block 8 valid cols)
#define NWH  80    // h@Wh blocks, 32 cols each
#define NBLK 237

// workspace layout (float offsets)
#define O_JOINT 0        // jointT[j][b]  (640x32)
#define O_HT    20480    // hT[j][b]      (640x32)
#define O_HWH   40960    // hwhT[col][b]  (2560x32)
#define O_CT    122880   // cT[j][b]
#define O_PNT   143360   // pnT[j][b]
#define O_PM    163840   // partial max    [157*32]
#define O_PS    168864   // partial sumexp [157*32]
#define O_PI    173888   // partial argmax [157*32] (int bits)
#define O_TOK   178912   // tok ping-pong: 2 x 32 (int bits)
#define O_SC    178976   // scores[32]
#define O_XWXB  180224   // embed@Wx + b  (5000x2560), optional
#define XWXB_ELEMS ((size_t)VV * (size_t)H4)

__device__ __forceinline__ float sigf(float x) { return 1.0f / (1.0f + expf(-x)); }

// ---------------- precompute: xwxb[v][c] = sum_k embed[v][k]*Wx[k][c] + b[c]
// grid (10, 313) x 256 thr; block tile = 256 cols x 16 v rows; register tile 4x4.
__global__ __launch_bounds__(256) void precompute_k(const float* __restrict__ embed,
                                                    const float* __restrict__ Wx,
                                                    const float* __restrict__ bias,
                                                    float* __restrict__ xwxb) {
  __shared__ float embT[HH * 17];  // [k][vlocal], stride 17 to break bank alignment
  const int tid = threadIdx.x;
  const int v0 = blockIdx.y * 16;
  const int c0 = blockIdx.x * 256 + (tid & 63) * 4;
  const int vg = tid >> 6;  // 0..3 -> vlocal vg*4..vg*4+3
  for (int i = tid; i < 16 * 160; i += 256) {
    int vr = i / 160, kq = i - vr * 160;
    int v = v0 + vr; if (v >= VV) v = VV - 1;
    float4 e = *(const float4*)&embed[(size_t)v * HH + kq * 4];
    embT[(kq * 4 + 0) * 17 + vr] = e.x;
    embT[(kq * 4 + 1) * 17 + vr] = e.y;
    embT[(kq * 4 + 2) * 17 + vr] = e.z;
    embT[(kq * 4 + 3) * 17 + vr] = e.w;
  }
  __syncthreads();
  float acc[16];
#pragma unroll
  for (int i = 0; i < 16; ++i) acc[i] = 0.f;
#pragma unroll 4
  for (int k = 0; k < HH; ++k) {
    float4 wv = *(const float4*)&Wx[(size_t)k * H4 + c0];
#pragma unroll
    for (int i = 0; i < 4; ++i) {
      float e = embT[k * 17 + vg * 4 + i];
      acc[i * 4 + 0] += e * wv.x;
      acc[i * 4 + 1] += e * wv.y;
      acc[i * 4 + 2] += e * wv.z;
      acc[i * 4 + 3] += e * wv.w;
    }
  }
  float4 bv = *(const float4*)&bias[c0];
#pragma unroll
  for (int i = 0; i < 4; ++i) {
    int v = v0 + vg * 4 + i;
    if (v < VV) {
      float4 r;
      r.x = acc[i * 4 + 0] + bv.x; r.y = acc[i * 4 + 1] + bv.y;
      r.z = acc[i * 4 + 2] + bv.z; r.w = acc[i * 4 + 3] + bv.w;
      *(float4*)&xwxb[(size_t)v * H4 + c0] = r;
    }
  }
}

// ---------------- init: tok/scores, LSTM step from (h0=c0=0, tok=0), joint for t=0. grid 80 x 256.
__global__ __launch_bounds__(256) void init_k(const float* __restrict__ tn,
                                              const float* __restrict__ embed,
                                              const float* __restrict__ Wx,
                                              const float* __restrict__ bias,
                                              float* __restrict__ ws,
                                              const float* __restrict__ xwxb, int use_table) {
  const int tid = threadIdx.x, bid = blockIdx.x;
  const int b = tid & 31, c8 = tid >> 5;
  const int j = bid * 8 + c8;
  if (bid == 0 && tid < 32) {
    ws[O_TOK + tid] = __int_as_float(0);
    ws[O_TOK + 32 + tid] = __int_as_float(0);
    ws[O_SC + tid] = 0.f;
  }
  float g4[4];
  if (use_table) {
#pragma unroll
    for (int g = 0; g < 4; ++g) g4[g] = xwxb[g * HH + j];  // token 0 row
  } else {
#pragma unroll
    for (int g = 0; g < 4; ++g) g4[g] = bias[g * HH + j];
#pragma unroll 4
    for (int k = 0; k < HH; ++k) {
      float xv = embed[k];  // token 0 row
#pragma unroll
      for (int g = 0; g < 4; ++g) g4[g] += xv * Wx[(size_t)k * H4 + g * HH + j];
    }
  }
  float c1 = sigf(g4[0]) * tanhf(g4[2]);  // f-gate * c0(=0) dropped
  float h1 = sigf(g4[3]) * tanhf(c1);
  ws[O_CT + j * 32 + b] = c1;
  ws[O_HT + j * 32 + b] = h1;
  ws[O_PNT + j * 32 + b] = h1;
  ws[O_JOINT + j * 32 + b] = tanhf(tn[(size_t)b * TT * HH + j] + h1);
}

// ---------------- w1: both GEMMs, 16-way K-split, 512 threads (2 waves/SIMD)
__global__ __launch_bounds__(512, 2) void w1_k(const float* __restrict__ Wc,
                                               const float* __restrict__ Wh,
                                               const float* __restrict__ bc,
                                               float* __restrict__ ws) {
  __shared__ float part[8 * 1088];  // [wave8][col32 stride 34][b32]
  __shared__ float lm[16 * 33], lsv[16 * 33];
  __shared__ int   lix[16 * 33];
  const int tid = threadIdx.x, bid = blockIdx.x;
  const int lane = tid & 63, wv = tid >> 6;     // wave 0..7
  const int sub = lane >> 5, col = lane & 31;   // sub k-half within wave
  const int p = wv * 2 + sub;                   // 16-way k split
  const int kbase = p * 40;
  const bool is_log = (bid < NLOG);

  float acc[32];
#pragma unroll
  for (int i = 0; i < 32; ++i) acc[i] = 0.f;

  if (is_log) {
    const int c = bid * 32 + col;
    const int cc = (c < VV) ? c : (VV - 1);
    const float* jb = ws + O_JOINT + kbase * 32;
    const float* wp = Wc + (size_t)kbase * VV + cc;
#pragma unroll 4
    for (int kk = 0; kk < 40; ++kk) {
      float w = wp[(size_t)kk * VV];
      const float4* jp = (const float4*)(jb + kk * 32);
#pragma unroll
      for (int r = 0; r < 8; ++r) {
        float4 j4 = jp[r];
        acc[r * 4 + 0] += j4.x * w; acc[r * 4 + 1] += j4.y * w;
        acc[r * 4 + 2] += j4.z * w; acc[r * 4 + 3] += j4.w * w;
      }
    }
  } else {
    const int c = (bid - NLOG) * 32 + col;
    const float* hb = ws + O_HT + kbase * 32;
    const float* wp = Wh + (size_t)kbase * H4 + c;
#pragma unroll 4
    for (int kk = 0; kk < 40; ++kk) {
      float w = wp[(size_t)kk * H4];
      const float4* jp = (const float4*)(hb + kk * 32);
#pragma unroll
      for (int r = 0; r < 8; ++r) {
        float4 j4 = jp[r];
        acc[r * 4 + 0] += j4.x * w; acc[r * 4 + 1] += j4.y * w;
        acc[r * 4 + 2] += j4.z * w; acc[r * 4 + 3] += j4.w * w;
      }
    }
  }
  // combine the wave's two k-halves in-register
#pragma unroll
  for (int i = 0; i < 32; ++i) acc[i] += __shfl_xor(acc[i], 32);
  if (sub == 0) {
    float* pb = part + wv * 1088 + col * 34;
#pragma unroll
    for (int r2 = 0; r2 < 16; ++r2)
      *(float2*)&pb[r2 * 2] = make_float2(acc[r2 * 2], acc[r2 * 2 + 1]);
  }
  __syncthreads();

  // reduce the 8 wave-partials; 512 threads: b=tid&31, colg=tid>>5 in [0,16) -> 2 cols each
  const int b = tid & 31, colg = tid >> 5;
  float lg[2];
#pragma unroll
  for (int i = 0; i < 2; ++i) {
    const int cl = colg * 2 + i;
    float s = 0.f;
#pragma unroll
    for (int q = 0; q < 8; ++q) s += part[q * 1088 + cl * 34 + b];
    lg[i] = s;
  }
  if (is_log) {
    float m = -FLT_MAX; int ix = 0;
    float lv[2];
#pragma unroll
    for (int i = 0; i < 2; ++i) {
      int cg = bid * 32 + colg * 2 + i;
      int cgc = (cg < VV) ? cg : (VV - 1);
      float l = (cg < VV) ? lg[i] + bc[cgc] : -FLT_MAX;
      lv[i] = l;
      if (l > m) { m = l; ix = cg; }
    }
    float e = 0.f;
    if (m > -FLT_MAX) {
#pragma unroll
      for (int i = 0; i < 2; ++i) e += expf(lv[i] - m);
    }
    lm[colg * 33 + b] = m; lsv[colg * 33 + b] = e; lix[colg * 33 + b] = ix;
    __syncthreads();
    if (tid < 32) {
      float m2 = lm[tid], s2 = lsv[tid]; int ix2 = lix[tid];
#pragma unroll
      for (int q = 1; q < 16; ++q) {
        float M = lm[q * 33 + tid], S = lsv[q * 33 + tid]; int I = lix[q * 33 + tid];
        if (M > m2) { s2 = s2 * expf(m2 - M) + S; m2 = M; ix2 = I; }
        else if (M > -FLT_MAX) { s2 += S * expf(M - m2); }
      }
      ws[O_PM + bid * 32 + tid] = m2;
      ws[O_PS + bid * 32 + tid] = s2;
      ws[O_PI + bid * 32 + tid] = __int_as_float(ix2);
    }
  } else {
    const int chb = (bid - NLOG) * 32 + colg * 2;
#pragma unroll
    for (int i = 0; i < 2; ++i)
      ws[O_HWH + (chb + i) * 32 + b] = lg[i];  // hwhT[col][b], coalesced
  }
}

// ---------------- w2 (table path): reduce -> tok ; gates ; state update ; next joint. grid 80 x 256.
__global__ __launch_bounds__(256) void w2_k(const float* __restrict__ tn,
                                            const float* __restrict__ xwxb,
                                            float* __restrict__ out,
                                            float* __restrict__ ws, int t) {
  __shared__ float rm[8 * 33], rs[8 * 33];
  __shared__ int ri[8 * 33];
  __shared__ int s_tok[32];
  __shared__ int s_upd[32];
  const int tid = threadIdx.x, bid = blockIdx.x;
  const int r = tid & 31, c8 = tid >> 5;
  {
    int g0 = (c8 * NLOG) >> 3, g1 = ((c8 + 1) * NLOG) >> 3;
    float m = -FLT_MAX, s = 0.f; int ix = 0;
    for (int g = g0; g < g1; ++g) {
      float M = ws[O_PM + g * 32 + r];
      float S = ws[O_PS + g * 32 + r];
      int I = __float_as_int(ws[O_PI + g * 32 + r]);
      if (M > m) { s = s * expf(m - M) + S; m = M; ix = I; }
      else { s += S * expf(M - m); }
    }
    rm[c8 * 33 + r] = m; rs[c8 * 33 + r] = s; ri[c8 * 33 + r] = ix;
  }
  __syncthreads();
  if (tid < 32) {
    float m = rm[tid], s = rs[tid]; int ix = ri[tid];
#pragma unroll
    for (int q = 1; q < 8; ++q) {
      float M = rm[q * 33 + tid], S = rs[q * 33 + tid]; int I = ri[q * 33 + tid];
      if (M > m) { s = s * expf(m - M) + S; m = M; ix = I; }
      else { s += S * expf(M - m); }
    }
    int pos = ix;
    int upd = (pos != 0) ? 1 : 0;
    int tk = __float_as_int(ws[O_TOK + (t & 1) * 32 + tid]);
    int ntk = upd ? pos : tk;
    s_tok[tid] = ntk;
    s_upd[tid] = upd;
    if (bid == 0) {
      ws[O_TOK + ((t + 1) & 1) * 32 + tid] = __int_as_float(ntk);
      float sc = ws[O_SC + tid];
      if (upd) sc -= logf(s);  // max logp = -log(sumexp rel max)
      ws[O_SC + tid] = sc;
      out[BB + (size_t)tid * TT + t] = upd ? (float)pos : 0.0f;
      if (t == TT - 1) out[tid] = sc;
    }
  }
  __syncthreads();
  const int j = bid * 8 + c8, b = r;
  const int tk = s_tok[b];
  float g4[4];
#pragma unroll
  for (int g = 0; g < 4; ++g) {
    int colx = g * HH + j;
    g4[g] = ws[O_HWH + colx * 32 + b] + xwxb[(size_t)tk * H4 + colx];
  }
  float ci = ws[O_CT + j * 32 + b];
  float c2 = sigf(g4[1]) * ci + sigf(g4[0]) * tanhf(g4[2]);
  float h2 = sigf(g4[3]) * tanhf(c2);
  float pv;
  if (s_upd[b]) {
    ws[O_CT + j * 32 + b] = c2;
    ws[O_HT + j * 32 + b] = h2;
    ws[O_PNT + j * 32 + b] = h2;
    pv = h2;
  } else {
    pv = ws[O_PNT + j * 32 + b];
  }
  if (t + 1 < TT)
    ws[O_JOINT + j * 32 + b] = tanhf(tn[((size_t)b * TT + (t + 1)) * HH + j] + pv);
}

// ---------------- w2 fallback (no table): reduce ; inline x@Wx ; gates ; update. grid NBLK x 256.
__global__ __launch_bounds__(256) void w2f_k(const float* __restrict__ tn,
                                             const float* __restrict__ embed,
                                             const float* __restrict__ Wx,
                                             const float* __restrict__ bias,
                                             float* __restrict__ out,
                                             float* __restrict__ ws, int t) {
  __shared__ float rm[8][BB];
  __shared__ float rs[8][BB];
  __shared__ int ri[8][BB];
  __shared__ int s_tok[BB];
  __shared__ int s_upd[BB];
  __shared__ float xl[BB * 321];
  const int tid = threadIdx.x, bid = blockIdx.x;
  const int r = tid & 31, c8 = tid >> 5;
  {
    int g0 = (c8 * NLOG) >> 3, g1 = ((c8 + 1) * NLOG) >> 3;
    float m = -FLT_MAX, s = 0.0f; int ix = 0;
    for (int g = g0; g < g1; ++g) {
      float M = ws[O_PM + g * 32 + r];
      float S = ws[O_PS + g * 32 + r];
      int I = __float_as_int(ws[O_PI + g * 32 + r]);
      if (M > m) { s = s * expf(m - M) + S; m = M; ix = I; }
      else       { s += S * expf(M - m); }
    }
    rm[c8][r] = m; rs[c8][r] = s; ri[c8][r] = ix;
  }
  __syncthreads();
  if (tid < BB) {
    float m = rm[0][tid], s = rs[0][tid]; int ix = ri[0][tid];
#pragma unroll
    for (int q = 1; q < 8; ++q) {
      float M = rm[q][tid], S = rs[q][tid]; int I = ri[q][tid];
      if (M > m) { s = s * expf(m - M) + S; m = M; ix = I; }
      else       { s += S * expf(M - m); }
    }
    int pos = ix;
    int upd = (pos != 0) ? 1 : 0;
    int tk = __float_as_int(ws[O_TOK + (t & 1) * 32 + tid]);
    int ntk = upd ? pos : tk;
    s_tok[tid] = ntk;
    s_upd[tid] = upd;
    if (bid == 0) {
      ws[O_TOK + ((t + 1) & 1) * 32 + tid] = __int_as_float(ntk);
      float sc = ws[O_SC + tid];
      if (upd) sc += -logf(s);
      ws[O_SC + tid] = sc;
      out[BB + (size_t)tid * TT + t] = upd ? (float)pos : 0.0f;
      if (t == TT - 1) out[tid] = sc;
    }
  }
  __syncthreads();

  const int j0 = (bid * HH) / NBLK, j1 = ((bid + 1) * HH) / NBLK;
  const int nj = j1 - j0;
  const int p = tid;
  const bool act = p < nj * BB;
  int b = 0, j = 0;
  float g4[4] = {0, 0, 0, 0};
  if (act) {
    b = p & 31; j = j0 + (p >> 5);
#pragma unroll
    for (int g = 0; g < 4; ++g) {
      int col = g * HH + j;
      g4[g] = ws[O_HWH + (size_t)col * 32 + b] + bias[col];
    }
  }
  for (int half = 0; half < 2; ++half) {
    int k0 = half * 320;
    __syncthreads();
    for (int i = tid; i < BB * 320; i += 256) {
      int bb = i / 320;
      int kk = i - bb * 320;
      xl[bb * 321 + kk] = embed[(size_t)s_tok[bb] * HH + k0 + kk];
    }
    __syncthreads();
    if (act) {
      for (int k = 0; k < 320; ++k) {
        float xv = xl[b * 321 + k];
#pragma unroll
        for (int g = 0; g < 4; ++g) g4[g] += xv * Wx[(size_t)(k0 + k) * H4 + (g * HH + j)];
      }
    }
  }
  if (act) {
    float ci = ws[O_CT + j * BB + b];
    float c2 = sigf(g4[1]) * ci + sigf(g4[0]) * tanhf(g4[2]);
    float h2 = sigf(g4[3]) * tanhf(c2);
    float pv;
    if (s_upd[b]) {
      ws[O_CT + j * BB + b] = c2;
      ws[O_HT + j * BB + b] = h2;
      ws[O_PNT + j * BB + b] = h2;
      pv = h2;
    } else {
      pv = ws[O_PNT + j * BB + b];
    }
    if (t + 1 < TT)
      ws[O_JOINT + j * BB + b] = tanhf(tn[((size_t)b * TT + (t + 1)) * HH + j] + pv);
  }
}

extern "C" void kernel_launch(void* const* d_in, const int* in_sizes, int n_in,
                              void* d_out, int out_size, void* d_ws, size_t ws_size,
                              hipStream_t stream) {
  const float* tn    = (const float*)d_in[0];
  const float* embed = (const float*)d_in[1];
  const float* Wx    = (const float*)d_in[2];
  const float* Wh    = (const float*)d_in[3];
  const float* bias  = (const float*)d_in[4];
  const float* Wc    = (const float*)d_in[5];
  const float* bc    = (const float*)d_in[6];
  float* out = (float*)d_out;
  float* ws  = (float*)d_ws;
  const float* xwxb = ws + O_XWXB;

  const size_t need_table = (size_t)(O_XWXB + XWXB_ELEMS) * sizeof(float);
  const int use_table = (ws_size >= need_table) ? 1 : 0;

  if (use_table)
    hipLaunchKernelGGL(precompute_k, dim3(10, 313), dim3(256), 0, stream,
                       embed, Wx, bias, (float*)xwxb);
  hipLaunchKernelGGL(init_k, dim3(80), dim3(256), 0, stream, tn, embed, Wx, bias, ws,
                     xwxb, use_table);
  for (int t = 0; t < TT; ++t) {
    hipLaunchKernelGGL(w1_k, dim3(NBLK), dim3(512), 0, stream, Wc, Wh, bc, ws);
    if (use_table)
      hipLaunchKernelGGL(w2_k, dim3(80), dim3(256), 0, stream, tn, xwxb, out, ws, t);
    else
      hipLaunchKernelGGL(w2f_k, dim3(NBLK), dim3(256), 0, stream, tn, embed, Wx, bias, out, ws, t);
  }
}